// Round 3
// baseline (430.145 us; speedup 1.0000x reference)
//
#include <hip/hip_runtime.h>

// QECC statevector: 23 qubits, DIM = 2^23 amplitudes, N0 = 2 vectors per code.
// Gate ind0 acts on statevector bit p = 22 - ind0:  new_d = sum_b old_b * U[b,d].
// Split: k_low does statevector bits 0..12 (gates q=22..10), k_high bits 13..22
// (gates q=9..0) + fused overlap dot. Intermediate ws is TRANSPOSED:
//   W(i,h,l) = i*DIM + (l>>3)*8192 + h*8 + (l&7)     (h = idx>>13, l = idx&8191)
// so k_high reads one contiguous 64 KB chunk per (block,i).
//
// R5: R4 still showed VGPR=128 + 98 MB scratch spills even with the source-level
// prefetch removed -> the SCHEDULER recreates it: ws(i=1) loads have no data dep
// on section 1 (written by a prior kernel; __syncthreads doesn't fence global-load
// motion), so they hoist above dot0 and blow liveness exactly like R3's explicit
// prefetch (identical VGPR=128 signature). Fix: pin the schedule with
// asm volatile memory clobbers + sched_barrier(0) bracketing each dot, bounding
// peak liveness to ~110 regs. Keep dot-split + pair-chunk XCD swizzle +
// nontemporal streaming loads (R3/R4 proved c1 becomes ~fully cache-served:
// FETCH - spills = 129 MB = ws only).
//
// NOTE on __launch_bounds__: measured R2 showed hipcc treats the 2nd arg as
// CUDA-style min BLOCKS per CU: (512,4) -> 32 waves/CU -> 64-VGPR cap -> 401 MB
// of spill traffic. (512,2) -> cap 128; LDS (64 KB/block) limits to 2 blocks/CU.
#define DIM_ (1 << 23)
#define N0_ 2

typedef float f32x4 __attribute__((ext_vector_type(4)));

// Hard scheduling fence: no load/store or scheduler motion across this point.
#define SCHED_FENCE()                          \
    do {                                       \
        asm volatile("" ::: "memory");         \
        __builtin_amdgcn_sched_barrier(0);     \
    } while (0)

// overlap accumulators {R00,I00,R01,I01,R10,I10,R11,I11}; zeroed each launch
__device__ float g_acc[8];

// LDS bank swizzle (bits 0,1 ^= bits 5,6 ; bits 2..4 ^= bits 7..9), bijective.
__device__ __forceinline__ int swz(int x) {
    return x ^ ((x >> 5) & 3) ^ (((x >> 7) & 7) << 2);
}

__device__ __forceinline__ void gload(const float* __restrict__ ur,
                                      const float* __restrict__ ui, int q,
                                      float2& u00, float2& u01, float2& u10, float2& u11) {
    u00 = make_float2(ur[q * 4 + 0], ui[q * 4 + 0]);
    u01 = make_float2(ur[q * 4 + 1], ui[q * 4 + 1]);
    u10 = make_float2(ur[q * 4 + 2], ui[q * 4 + 2]);
    u11 = make_float2(ur[q * 4 + 3], ui[q * 4 + 3]);
}

// out0 = u00*a0 + u10*a1 ; out1 = u01*a0 + u11*a1   (complex, einsum convention)
__device__ __forceinline__ void bfly(float2& a0, float2& a1,
                                     float2 u00, float2 u01, float2 u10, float2 u11) {
    float2 n0, n1;
    n0.x = a0.x * u00.x - a0.y * u00.y + a1.x * u10.x - a1.y * u10.y;
    n0.y = a0.x * u00.y + a0.y * u00.x + a1.x * u10.y + a1.y * u10.x;
    n1.x = a0.x * u01.x - a0.y * u01.y + a1.x * u11.x - a1.y * u11.y;
    n1.y = a0.x * u01.y + a0.y * u01.x + a1.x * u11.y + a1.y * u11.x;
    a0 = n0; a1 = n1;
}

// Butterfly all pairs of the 16-register file v[] differing in bit log2(S), gate Q.
#define BFLY16(S, Q)                                                           \
    do {                                                                       \
        float2 u00, u01, u10, u11;                                             \
        gload(ur, ui, (Q), u00, u01, u10, u11);                                \
        _Pragma("unroll")                                                      \
        for (int m0 = 0; m0 < 16; ++m0)                                        \
            if (!(m0 & (S))) bfly(v[m0], v[m0 + (S)], u00, u01, u10, u11);     \
    } while (0)

// ---------------------------------------------------------------------------
// K1: low 13 bits. Block (H, i) owns the contiguous chunk idx = H*8192 + l.
// 512 thr x 16 complex regs. Phases (4 bits each in regs, LDS remaps between):
//   A: l bits {0,1,11,12} -> q22,q21,q11,q10      (from float4 load layout)
//   B: l bits {2..5}      -> q20..q17
//   C: l bits {6..9}      -> q16..q13
//   readout: pairs (x, x^1024) -> q12, then store transposed (or identity for
//   the in-place fallback).
// ---------------------------------------------------------------------------
template <bool INTER>
__global__ __launch_bounds__(512, 2) void k_low(
    const float* __restrict__ inr, const float* __restrict__ ini,
    const float* __restrict__ ur, const float* __restrict__ ui,
    float2* __restrict__ outI, float* __restrict__ outR, float* __restrict__ outJ) {
    __shared__ float2 buf[8192];  // 64 KB
    const int t = threadIdx.x;
    const int H = blockIdx.x;                 // high-10-bit value this block owns
    const int base = blockIdx.y * DIM_ + (H << 13);

    float2 v[16];
    // load: reg m = (k<<2)|j  <->  l = (k<<11)|(t<<2)|j   (nt: c0 is read-once)
#pragma unroll
    for (int k = 0; k < 4; ++k) {
        const int y = (k << 11) | (t << 2);
        const f32x4 re = __builtin_nontemporal_load((const f32x4*)(inr + base + y));
        const f32x4 im = __builtin_nontemporal_load((const f32x4*)(ini + base + y));
        v[k * 4 + 0] = make_float2(re.x, im.x);
        v[k * 4 + 1] = make_float2(re.y, im.y);
        v[k * 4 + 2] = make_float2(re.z, im.z);
        v[k * 4 + 3] = make_float2(re.w, im.w);
    }
    // Phase A: m0=l0->q22, m1=l1->q21, m2=l11->q11, m3=l12->q10
    BFLY16(1, 22);
    BFLY16(2, 21);
    BFLY16(4, 11);
    BFLY16(8, 10);
#pragma unroll
    for (int m = 0; m < 16; ++m)
        buf[swz(((m >> 2) << 11) | (t << 2) | (m & 3))] = v[m];
    __syncthreads();
    // Phase B: m = l bits 2..5 ; x = (t&3) | (m<<2) | ((t>>2)<<6)
#pragma unroll
    for (int m = 0; m < 16; ++m)
        v[m] = buf[swz((t & 3) | (m << 2) | ((t >> 2) << 6))];
    BFLY16(1, 20);
    BFLY16(2, 19);
    BFLY16(4, 18);
    BFLY16(8, 17);
#pragma unroll
    for (int m = 0; m < 16; ++m)
        buf[swz((t & 3) | (m << 2) | ((t >> 2) << 6))] = v[m];  // same slots: no race
    __syncthreads();
    // Phase C: m = l bits 6..9 ; x = (t&63) | (m<<6) | ((t>>6)<<10)
#pragma unroll
    for (int m = 0; m < 16; ++m)
        v[m] = buf[swz((t & 63) | (m << 6) | ((t >> 6) << 10))];
    BFLY16(1, 16);
    BFLY16(2, 15);
    BFLY16(4, 14);
    BFLY16(8, 13);
#pragma unroll
    for (int m = 0; m < 16; ++m)
        buf[swz((t & 63) | (m << 6) | ((t >> 6) << 10))] = v[m];
    __syncthreads();
    // Readout + q12 (l bit 10 = pairs x, x^1024), stores 2 complex per float4.
    {
        float2 u00, u01, u10, u11;
        gload(ur, ui, 12, u00, u01, u10, u11);
#pragma unroll
        for (int rp = 0; rp < 4; ++rp) {
            const int x0 = (rp << 11) | (t << 1);  // even, bit10 = 0
            float2 a0 = buf[swz(x0)];
            float2 a1 = buf[swz(x0 | 1)];
            float2 b0 = buf[swz(x0 | 1024)];
            float2 b1 = buf[swz(x0 | 1025)];
            bfly(a0, b0, u00, u01, u10, u11);
            bfly(a1, b1, u00, u01, u10, u11);
            if (INTER) {
                // transposed: o = (l>>3)*8192 + H*8 + (l&7); l&7 even -> 16B aligned
                const int l0 = x0, l1 = x0 | 1024;
                const int o0 = ((l0 >> 3) << 13) | (H << 3) | (l0 & 7);
                const int o1 = ((l1 >> 3) << 13) | (H << 3) | (l1 & 7);
                float2* p = outI + blockIdx.y * DIM_;
                *(float4*)(p + o0) = make_float4(a0.x, a0.y, a1.x, a1.y);
                *(float4*)(p + o1) = make_float4(b0.x, b0.y, b1.x, b1.y);
            } else {
                // identity layout, in-place safe (block writes only its own chunk)
                *(float2*)(outR + base + x0) = make_float2(a0.x, a1.x);
                *(float2*)(outJ + base + x0) = make_float2(a0.y, a1.y);
                *(float2*)(outR + base + (x0 | 1024)) = make_float2(b0.x, b1.x);
                *(float2*)(outJ + base + (x0 | 1024)) = make_float2(b0.y, b1.y);
            }
        }
    }
}

// ---------------------------------------------------------------------------
// K2 helpers: ws chunk load (into raw regs), unpack, 10-gate transform, dot.
// ---------------------------------------------------------------------------
template <bool INTER>
__device__ __forceinline__ void load_ws(f32x4 (&raw)[8], const int t, const int g, const int i,
                                        const float2* __restrict__ wsI,
                                        const float* __restrict__ wsR,
                                        const float* __restrict__ wsJ) {
    if constexpr (INTER) {
        // contiguous 64 KB chunk; nontemporal: ws is read exactly once
        const f32x4* wsv = (const f32x4*)(wsI + i * DIM_ + (g << 13));
#pragma unroll
        for (int k = 0; k < 4; ++k)
#pragma unroll
            for (int jh = 0; jh < 2; ++jh)
                raw[k * 2 + jh] =
                    __builtin_nontemporal_load(wsv + ((k << 10) | (t << 1) | jh));
    } else {
        // identity-layout fallback: idx = h*8192 + g*8 + e
#pragma unroll
        for (int k = 0; k < 4; ++k) {
            const int y0 = (k << 11) | (t << 2);
            const int a = ((y0 >> 3) << 13) | (g << 3) | (y0 & 7);
            raw[k * 2 + 0] = *(const f32x4*)(wsR + i * DIM_ + a);
            raw[k * 2 + 1] = *(const f32x4*)(wsJ + i * DIM_ + a);
        }
    }
}

template <bool INTER>
__device__ __forceinline__ void unpack_ws(const f32x4 (&raw)[8], float2 (&v)[16]) {
    if constexpr (INTER) {
#pragma unroll
        for (int k = 0; k < 4; ++k)
#pragma unroll
            for (int jh = 0; jh < 2; ++jh) {
                const f32x4 f = raw[k * 2 + jh];
                v[k * 4 + jh * 2 + 0] = make_float2(f.x, f.y);
                v[k * 4 + jh * 2 + 1] = make_float2(f.z, f.w);
            }
    } else {
#pragma unroll
        for (int k = 0; k < 4; ++k) {
            const f32x4 re = raw[k * 2 + 0];
            const f32x4 im = raw[k * 2 + 1];
            v[k * 4 + 0] = make_float2(re.x, im.x);
            v[k * 4 + 1] = make_float2(re.y, im.y);
            v[k * 4 + 2] = make_float2(re.z, im.z);
            v[k * 4 + 3] = make_float2(re.w, im.w);
        }
    }
}

// 10-gate high transform. On entry v holds the 8192-chunk in load layout
// (y = h*8 + e enumerated as phase-A layout); on exit v is in phase-C layout:
// y = (t&127) | (m<<7) | ((t>>7)<<11). Ends after phase-C BFLYs (no trailing
// sync; caller must __syncthreads before buf is reused).
__device__ __forceinline__ void high_transform(float2 (&v)[16], float2* buf, const int t,
                                               const float* __restrict__ ur,
                                               const float* __restrict__ ui) {
    // Phase A: reg m2,m3 = y bits 11,12 = h bits 8,9 -> gates q1,q0
    BFLY16(4, 1);
    BFLY16(8, 0);
#pragma unroll
    for (int m = 0; m < 16; ++m)
        buf[swz(((m >> 2) << 11) | (t << 2) | (m & 3))] = v[m];
    __syncthreads();
    // Phase B: m = h bits 0..3 = y bits 3..6 ; x = (t&7) | (m<<3) | ((t>>3)<<7)
#pragma unroll
    for (int m = 0; m < 16; ++m)
        v[m] = buf[swz((t & 7) | (m << 3) | ((t >> 3) << 7))];
    BFLY16(1, 9);
    BFLY16(2, 8);
    BFLY16(4, 7);
    BFLY16(8, 6);
#pragma unroll
    for (int m = 0; m < 16; ++m)
        buf[swz((t & 7) | (m << 3) | ((t >> 3) << 7))] = v[m];  // same slots
    __syncthreads();
    // Phase C: m = h bits 4..7 = y bits 7..10 ; x = (t&127) | (m<<7) | ((t>>7)<<11)
#pragma unroll
    for (int m = 0; m < 16; ++m)
        v[m] = buf[swz((t & 127) | (m << 7) | ((t >> 7) << 11))];
    BFLY16(1, 5);
    BFLY16(2, 4);
    BFLY16(4, 3);
    BFLY16(8, 2);
}

// Partial dot: overlap_{iJ} += conj(v_i) * c1_J for J=0,1 into acc[J0..J0+3].
// Same per-acc accumulation order as the original fused version (bitwise equal).
template <int J0>
__device__ __forceinline__ void dot_pass(const float2 (&v)[16], float (&acc)[8],
                                         const int t, const int g,
                                         const float* __restrict__ c1r,
                                         const float* __restrict__ c1i) {
#pragma unroll
    for (int m = 0; m < 16; ++m) {
        const int y = (t & 127) | (m << 7) | ((t >> 7) << 11);
        const int idx = ((y >> 3) << 13) | (g << 3) | (y & 7);
        const float ar = c1r[idx], ai = c1i[idx];
        const float br = c1r[DIM_ + idx], bi = c1i[DIM_ + idx];
        acc[J0 + 0] += v[m].x * ar + v[m].y * ai;
        acc[J0 + 1] += v[m].x * ai - v[m].y * ar;
        acc[J0 + 2] += v[m].x * br + v[m].y * bi;
        acc[J0 + 3] += v[m].x * bi - v[m].y * br;
    }
}

// ---------------------------------------------------------------------------
// K2: high 10 bits (gates q=9..0) + overlap dot. Block owns l-group g
// (l = g*8 + e). Per block:
//   load ws(i=0) -> transform0 -> [FENCE] dot0(v0) [FENCE] -> sync
//   -> load ws(i=1) -> transform1 -> [FENCE] dot1(v1) -> reduce.
// The FENCEs (memory clobber + sched_barrier(0)) stop the scheduler from
// hoisting ws(i=1)/c1 loads across section boundaries: R3 (explicit prefetch)
// and R4 (no prefetch, same counters) proved the hoist happens either way and
// costs 98-115 MB of scratch spills at the 128-VGPR cap. Bounded liveness:
// max(v32+acc8+transform temps, v32+acc8+c1 pipeline<=64) ~ 110 regs.
// Dot split spreads c1 BW across the block timeline; dot1's re-read of the
// same 256 KB is L2/LLC-served (c1 = 128 MB < LLC, ws reads nontemporal so
// they don't evict it). Pair-chunk XCD swizzle: blocks g and g^1 share every
// 64B c1 line (32B chunks each); same-XCD placement makes the partner half an
// L2 hit. b%8 = XCD (round-robin dispatch), so g = (b&7)*128 + b>>3.
// ---------------------------------------------------------------------------
template <bool INTER>
__global__ __launch_bounds__(512, 2) void k_high(
    const float2* __restrict__ wsI, const float* __restrict__ wsR, const float* __restrict__ wsJ,
    const float* __restrict__ c1r, const float* __restrict__ c1i,
    const float* __restrict__ ur, const float* __restrict__ ui) {
    __shared__ float2 buf[8192];  // 64 KB; reused as reduction scratch
    const int t = threadIdx.x;
    const int b = blockIdx.x;
    const int g = ((b & 7) << 7) | (b >> 3);  // bijective pair-chunk XCD swizzle
    float acc[8];
#pragma unroll
    for (int k = 0; k < 8; ++k) acc[k] = 0.f;

    {
        f32x4 raw[8];
        float2 v0[16];
        load_ws<INTER>(raw, t, g, 0, wsI, wsR, wsJ);
        unpack_ws<INTER>(raw, v0);
        high_transform(v0, buf, t, ur, ui);
        SCHED_FENCE();  // keep c1 loads out of the transform's live range
        dot_pass<0>(v0, acc, t, g, c1r, c1i);  // v0 dead after this
        SCHED_FENCE();  // keep ws(i=1) loads below dot0
    }

    __syncthreads();  // buf handoff between passes

    {
        f32x4 raw[8];
        float2 v1[16];
        load_ws<INTER>(raw, t, g, 1, wsI, wsR, wsJ);
        unpack_ws<INTER>(raw, v1);
        high_transform(v1, buf, t, ur, ui);
        SCHED_FENCE();  // keep c1 loads out of the transform's live range
        dot_pass<4>(v1, acc, t, g, c1r, c1i);
    }

    // wave (64) shuffle reduce -> cross-wave LDS -> one atomic per block
#pragma unroll
    for (int k = 0; k < 8; ++k)
#pragma unroll
        for (int off = 32; off > 0; off >>= 1)
            acc[k] += __shfl_down(acc[k], off, 64);
    __syncthreads();  // all waves past their buf reads before reuse as scratch
    float* red = (float*)buf;
    const int wave = t >> 6, lane = t & 63;
    if (lane == 0) {
#pragma unroll
        for (int k = 0; k < 8; ++k) red[wave * 8 + k] = acc[k];
    }
    __syncthreads();
    if (t < 8) {
        float s = 0.f;
#pragma unroll
        for (int w = 0; w < 8; ++w) s += red[w * 8 + t];
        atomicAdd(&g_acc[t], s);
    }
}

__global__ void k_zero() {
    if (threadIdx.x < 8) g_acc[threadIdx.x] = 0.f;
}

__global__ void k_fin(float* __restrict__ out) {
    if (threadIdx.x == 0) {
        float s = 0.f;
#pragma unroll
        for (int k = 0; k < 4; ++k)
            s += g_acc[2 * k] * g_acc[2 * k] + g_acc[2 * k + 1] * g_acc[2 * k + 1];
        out[0] = (float)N0_ - s;
    }
}

extern "C" void kernel_launch(void* const* d_in, const int* in_sizes, int n_in,
                              void* d_out, int out_size, void* d_ws, size_t ws_size,
                              hipStream_t stream) {
    const float* c0r = (const float*)d_in[0];
    const float* c0i = (const float*)d_in[1];
    const float* c1r = (const float*)d_in[2];
    const float* c1i = (const float*)d_in[3];
    const float* ur  = (const float*)d_in[4];
    const float* ui  = (const float*)d_in[5];
    float* out = (float*)d_out;

    const size_t need = (size_t)N0_ * DIM_ * sizeof(float2);  // 128 MB intermediate
    k_zero<<<1, 64, 0, stream>>>();
    dim3 g1(1024, N0_);
    if (d_ws != nullptr && ws_size >= need) {
        float2* wsI = (float2*)d_ws;
        k_low<true><<<g1, 512, 0, stream>>>(c0r, c0i, ur, ui, wsI, nullptr, nullptr);
        k_high<true><<<1024, 512, 0, stream>>>(wsI, nullptr, nullptr, c1r, c1i, ur, ui);
    } else {
        // fallback: identity layout, in place into code0 planes (harness restores
        // d_in from pristine copies before every timed launch)
        float* oR = (float*)c0r;
        float* oJ = (float*)c0i;
        k_low<false><<<g1, 512, 0, stream>>>(c0r, c0i, ur, ui, nullptr, oR, oJ);
        k_high<false><<<1024, 512, 0, stream>>>(nullptr, oR, oJ, c1r, c1i, ur, ui);
    }
    k_fin<<<1, 64, 0, stream>>>(out);
}

// Round 4
// 368.448 us; speedup vs baseline: 1.1674x; 1.1674x over previous
//
#include <hip/hip_runtime.h>

// QECC statevector: 23 qubits, DIM = 2^23 amplitudes, N0 = 2 vectors per code.
// Gate ind0 acts on statevector bit p = 22 - ind0:  new_d = sum_b old_b * U[b,d].
// Split: k_low does statevector bits 0..12 (gates q=22..10), k_high bits 13..22
// (gates q=9..0) + fused overlap dot. Intermediate ws is TRANSPOSED:
//   W(i,h,l) = i*DIM + (l>>3)*8192 + h*8 + (l&7)     (h = idx>>13, l = idx&8191)
// so k_high reads one contiguous 64 KB chunk per (block,i).
//
// R6: REVERT to the R2 fused-dot structure (measured: VGPR=108, zero spill,
// k_high 151 us). The R3-R5 dot-split arc proved:
//   - c1 pair-sharing via XCD swizzle works (c1 HBM traffic ~eliminated),
//   - but the split-dot structure ALWAYS compiles to VGPR=128 + ~100 MB of
//     scratch spills (R3 explicit prefetch, R4 plain, R5 sched fences: all
//     identical spill signature) -> the allocator spills v0 inside the
//     unrolled dot to batch c1 loads; not controllable at source level.
// So: fused dot (v0+v1 live forces the allocator to throttle load batching,
// proven no-spill) + pair-chunk XCD swizzle (k_high c1 reads AND k_low ws
// writes are 32B half-lines paired across g^1/H^1) + nontemporal loads on
// stream-once data (c0, ws) so c1 keeps L2/LLC residency.
//
// NOTE on __launch_bounds__: measured R2 showed hipcc treats the 2nd arg as
// CUDA-style min BLOCKS per CU: (512,4) -> 32 waves/CU -> 64-VGPR cap -> 401 MB
// of spill traffic. (512,2) -> cap 128; LDS (64 KB/block) limits to 2 blocks/CU.
#define DIM_ (1 << 23)
#define N0_ 2

typedef float f32x4 __attribute__((ext_vector_type(4)));

// overlap accumulators {R00,I00,R01,I01,R10,I10,R11,I11}; zeroed each launch
__device__ float g_acc[8];

// LDS bank swizzle (bits 0,1 ^= bits 5,6 ; bits 2..4 ^= bits 7..9), bijective.
__device__ __forceinline__ int swz(int x) {
    return x ^ ((x >> 5) & 3) ^ (((x >> 7) & 7) << 2);
}

// Pair-chunk XCD swizzle: round-robin dispatch puts linear block b on XCD b%8;
// map b -> ((b&7)<<7)|(b>>3) so each XCD owns a CONTIGUOUS 128-chunk range ->
// chunks c and c^1 (which share every 64B line of 32B-row accesses) land on
// the same XCD's L2. Bijective on [0,1024).
__device__ __forceinline__ int xcd_pair_swz(int b) {
    return ((b & 7) << 7) | (b >> 3);
}

__device__ __forceinline__ void gload(const float* __restrict__ ur,
                                      const float* __restrict__ ui, int q,
                                      float2& u00, float2& u01, float2& u10, float2& u11) {
    u00 = make_float2(ur[q * 4 + 0], ui[q * 4 + 0]);
    u01 = make_float2(ur[q * 4 + 1], ui[q * 4 + 1]);
    u10 = make_float2(ur[q * 4 + 2], ui[q * 4 + 2]);
    u11 = make_float2(ur[q * 4 + 3], ui[q * 4 + 3]);
}

// out0 = u00*a0 + u10*a1 ; out1 = u01*a0 + u11*a1   (complex, einsum convention)
__device__ __forceinline__ void bfly(float2& a0, float2& a1,
                                     float2 u00, float2 u01, float2 u10, float2 u11) {
    float2 n0, n1;
    n0.x = a0.x * u00.x - a0.y * u00.y + a1.x * u10.x - a1.y * u10.y;
    n0.y = a0.x * u00.y + a0.y * u00.x + a1.x * u10.y + a1.y * u10.x;
    n1.x = a0.x * u01.x - a0.y * u01.y + a1.x * u11.x - a1.y * u11.y;
    n1.y = a0.x * u01.y + a0.y * u01.x + a1.x * u11.y + a1.y * u11.x;
    a0 = n0; a1 = n1;
}

// Butterfly all pairs of the 16-register file v[] differing in bit log2(S), gate Q.
#define BFLY16(S, Q)                                                           \
    do {                                                                       \
        float2 u00, u01, u10, u11;                                             \
        gload(ur, ui, (Q), u00, u01, u10, u11);                                \
        _Pragma("unroll")                                                      \
        for (int m0 = 0; m0 < 16; ++m0)                                        \
            if (!(m0 & (S))) bfly(v[m0], v[m0 + (S)], u00, u01, u10, u11);     \
    } while (0)

// ---------------------------------------------------------------------------
// K1: low 13 bits. Block (H, i) owns the contiguous chunk idx = H*8192 + l.
// 512 thr x 16 complex regs. Phases (4 bits each in regs, LDS remaps between):
//   A: l bits {0,1,11,12} -> q22,q21,q11,q10      (from float4 load layout)
//   B: l bits {2..5}      -> q20..q17
//   C: l bits {6..9}      -> q16..q13
//   readout: pairs (x, x^1024) -> q12, then store transposed (or identity for
//   the in-place fallback).
// ---------------------------------------------------------------------------
template <bool INTER>
__global__ __launch_bounds__(512, 2) void k_low(
    const float* __restrict__ inr, const float* __restrict__ ini,
    const float* __restrict__ ur, const float* __restrict__ ui,
    float2* __restrict__ outI, float* __restrict__ outR, float* __restrict__ outJ) {
    __shared__ float2 buf[8192];  // 64 KB
    const int t = threadIdx.x;
    const int H = xcd_pair_swz(blockIdx.x);   // high-10-bit value this block owns
    const int base = blockIdx.y * DIM_ + (H << 13);

    float2 v[16];
    // load: reg m = (k<<2)|j  <->  l = (k<<11)|(t<<2)|j   (nt: c0 is read-once)
#pragma unroll
    for (int k = 0; k < 4; ++k) {
        const int y = (k << 11) | (t << 2);
        const f32x4 re = __builtin_nontemporal_load((const f32x4*)(inr + base + y));
        const f32x4 im = __builtin_nontemporal_load((const f32x4*)(ini + base + y));
        v[k * 4 + 0] = make_float2(re.x, im.x);
        v[k * 4 + 1] = make_float2(re.y, im.y);
        v[k * 4 + 2] = make_float2(re.z, im.z);
        v[k * 4 + 3] = make_float2(re.w, im.w);
    }
    // Phase A: m0=l0->q22, m1=l1->q21, m2=l11->q11, m3=l12->q10
    BFLY16(1, 22);
    BFLY16(2, 21);
    BFLY16(4, 11);
    BFLY16(8, 10);
#pragma unroll
    for (int m = 0; m < 16; ++m)
        buf[swz(((m >> 2) << 11) | (t << 2) | (m & 3))] = v[m];
    __syncthreads();
    // Phase B: m = l bits 2..5 ; x = (t&3) | (m<<2) | ((t>>2)<<6)
#pragma unroll
    for (int m = 0; m < 16; ++m)
        v[m] = buf[swz((t & 3) | (m << 2) | ((t >> 2) << 6))];
    BFLY16(1, 20);
    BFLY16(2, 19);
    BFLY16(4, 18);
    BFLY16(8, 17);
#pragma unroll
    for (int m = 0; m < 16; ++m)
        buf[swz((t & 3) | (m << 2) | ((t >> 2) << 6))] = v[m];  // same slots: no race
    __syncthreads();
    // Phase C: m = l bits 6..9 ; x = (t&63) | (m<<6) | ((t>>6)<<10)
#pragma unroll
    for (int m = 0; m < 16; ++m)
        v[m] = buf[swz((t & 63) | (m << 6) | ((t >> 6) << 10))];
    BFLY16(1, 16);
    BFLY16(2, 15);
    BFLY16(4, 14);
    BFLY16(8, 13);
#pragma unroll
    for (int m = 0; m < 16; ++m)
        buf[swz((t & 63) | (m << 6) | ((t >> 6) << 10))] = v[m];
    __syncthreads();
    // Readout + q12 (l bit 10 = pairs x, x^1024), stores 2 complex per float4.
    {
        float2 u00, u01, u10, u11;
        gload(ur, ui, 12, u00, u01, u10, u11);
#pragma unroll
        for (int rp = 0; rp < 4; ++rp) {
            const int x0 = (rp << 11) | (t << 1);  // even, bit10 = 0
            float2 a0 = buf[swz(x0)];
            float2 a1 = buf[swz(x0 | 1)];
            float2 b0 = buf[swz(x0 | 1024)];
            float2 b1 = buf[swz(x0 | 1025)];
            bfly(a0, b0, u00, u01, u10, u11);
            bfly(a1, b1, u00, u01, u10, u11);
            if (INTER) {
                // transposed: o = (l>>3)*8192 + H*8 + (l&7); l&7 even -> 16B aligned
                const int l0 = x0, l1 = x0 | 1024;
                const int o0 = ((l0 >> 3) << 13) | (H << 3) | (l0 & 7);
                const int o1 = ((l1 >> 3) << 13) | (H << 3) | (l1 & 7);
                float2* p = outI + blockIdx.y * DIM_;
                *(float4*)(p + o0) = make_float4(a0.x, a0.y, a1.x, a1.y);
                *(float4*)(p + o1) = make_float4(b0.x, b0.y, b1.x, b1.y);
            } else {
                // identity layout, in-place safe (block writes only its own chunk)
                *(float2*)(outR + base + x0) = make_float2(a0.x, a1.x);
                *(float2*)(outJ + base + x0) = make_float2(a0.y, a1.y);
                *(float2*)(outR + base + (x0 | 1024)) = make_float2(b0.x, b1.x);
                *(float2*)(outJ + base + (x0 | 1024)) = make_float2(b0.y, b1.y);
            }
        }
    }
}

// ---------------------------------------------------------------------------
// One 10-bit high-pass for vector i: loads 8192 complex, butterflies gates
// q=9..0, leaves the final values in v[] (phase-C register layout:
// y = (t&127) | (m<<7) | ((t>>7)<<11)). No trailing __syncthreads.
// ---------------------------------------------------------------------------
template <bool INTER>
__device__ __forceinline__ void high_pass(
    float2 (&v)[16], float2* buf, const int t, const int g, const int i,
    const float2* __restrict__ wsI, const float* __restrict__ wsR,
    const float* __restrict__ wsJ,
    const float* __restrict__ ur, const float* __restrict__ ui) {
    if constexpr (INTER) {
        // contiguous 64 KB chunk; nontemporal: ws is read exactly once
        const f32x4* wsv = (const f32x4*)(wsI + i * DIM_ + (g << 13));
#pragma unroll
        for (int k = 0; k < 4; ++k)
#pragma unroll
            for (int jh = 0; jh < 2; ++jh) {
                const f32x4 f =
                    __builtin_nontemporal_load(wsv + ((k << 10) | (t << 1) | jh));
                v[k * 4 + jh * 2 + 0] = make_float2(f.x, f.y);
                v[k * 4 + jh * 2 + 1] = make_float2(f.z, f.w);
            }
    } else {
        // identity-layout fallback: idx = h*8192 + g*8 + e
#pragma unroll
        for (int k = 0; k < 4; ++k) {
            const int y0 = (k << 11) | (t << 2);
            const int a = ((y0 >> 3) << 13) | (g << 3) | (y0 & 7);
            const f32x4 re = *(const f32x4*)(wsR + i * DIM_ + a);
            const f32x4 im = *(const f32x4*)(wsJ + i * DIM_ + a);
            v[k * 4 + 0] = make_float2(re.x, im.x);
            v[k * 4 + 1] = make_float2(re.y, im.y);
            v[k * 4 + 2] = make_float2(re.z, im.z);
            v[k * 4 + 3] = make_float2(re.w, im.w);
        }
    }
    // Phase A: reg m2,m3 = y bits 11,12 = h bits 8,9 -> gates q1,q0
    BFLY16(4, 1);
    BFLY16(8, 0);
#pragma unroll
    for (int m = 0; m < 16; ++m)
        buf[swz(((m >> 2) << 11) | (t << 2) | (m & 3))] = v[m];
    __syncthreads();
    // Phase B: m = h bits 0..3 = y bits 3..6 ; x = (t&7) | (m<<3) | ((t>>3)<<7)
#pragma unroll
    for (int m = 0; m < 16; ++m)
        v[m] = buf[swz((t & 7) | (m << 3) | ((t >> 3) << 7))];
    BFLY16(1, 9);
    BFLY16(2, 8);
    BFLY16(4, 7);
    BFLY16(8, 6);
#pragma unroll
    for (int m = 0; m < 16; ++m)
        buf[swz((t & 7) | (m << 3) | ((t >> 3) << 7))] = v[m];  // same slots
    __syncthreads();
    // Phase C: m = h bits 4..7 = y bits 7..10 ; x = (t&127) | (m<<7) | ((t>>7)<<11)
#pragma unroll
    for (int m = 0; m < 16; ++m)
        v[m] = buf[swz((t & 127) | (m << 7) | ((t >> 7) << 11))];
    BFLY16(1, 5);
    BFLY16(2, 4);
    BFLY16(4, 3);
    BFLY16(8, 2);
}

// ---------------------------------------------------------------------------
// K2: high 10 bits (gates q=9..0) + fused overlap dot. Block owns l-group g
// (l = g*8 + e; g pair-swizzled so g and g^1 share an XCD -> the 32B c1
// half-lines they split become same-L2 hits). Transforms i=0 into v0, i=1
// into v1 (both held in registers), then a SINGLE dot loop reading c1 once.
// Keeping v0+v1 live through the dot is what forces the allocator to throttle
// c1 load batching -- measured R2: VGPR=108, zero spill (vs the split-dot
// variants R3-R5: VGPR=128 + ~100 MB scratch spills, every time).
// ---------------------------------------------------------------------------
template <bool INTER>
__global__ __launch_bounds__(512, 2) void k_high(
    const float2* __restrict__ wsI, const float* __restrict__ wsR, const float* __restrict__ wsJ,
    const float* __restrict__ c1r, const float* __restrict__ c1i,
    const float* __restrict__ ur, const float* __restrict__ ui) {
    __shared__ float2 buf[8192];  // 64 KB; reused as reduction scratch
    const int t = threadIdx.x;
    const int g = xcd_pair_swz(blockIdx.x);  // l-group, 1024 blocks
    float acc[8];
#pragma unroll
    for (int k = 0; k < 8; ++k) acc[k] = 0.f;

    float2 v0[16], v1[16];
    high_pass<INTER>(v0, buf, t, g, 0, wsI, wsR, wsJ, ur, ui);
    __syncthreads();  // buf handoff between passes
    high_pass<INTER>(v1, buf, t, g, 1, wsI, wsR, wsJ, ur, ui);

    // Fused dot: overlap_ij += conj(c0'_i) * c1_j ; c1 read ONCE.
#pragma unroll
    for (int m = 0; m < 16; ++m) {
        const int y = (t & 127) | (m << 7) | ((t >> 7) << 11);
        const int idx = ((y >> 3) << 13) | (g << 3) | (y & 7);
        const float ar = c1r[idx], ai = c1i[idx];
        const float br = c1r[DIM_ + idx], bi = c1i[DIM_ + idx];
        acc[0] += v0[m].x * ar + v0[m].y * ai;
        acc[1] += v0[m].x * ai - v0[m].y * ar;
        acc[2] += v0[m].x * br + v0[m].y * bi;
        acc[3] += v0[m].x * bi - v0[m].y * br;
        acc[4] += v1[m].x * ar + v1[m].y * ai;
        acc[5] += v1[m].x * ai - v1[m].y * ar;
        acc[6] += v1[m].x * br + v1[m].y * bi;
        acc[7] += v1[m].x * bi - v1[m].y * br;
    }

    // wave (64) shuffle reduce -> cross-wave LDS -> one atomic per block
#pragma unroll
    for (int k = 0; k < 8; ++k)
#pragma unroll
        for (int off = 32; off > 0; off >>= 1)
            acc[k] += __shfl_down(acc[k], off, 64);
    __syncthreads();  // all waves past their buf reads before reuse as scratch
    float* red = (float*)buf;
    const int wave = t >> 6, lane = t & 63;
    if (lane == 0) {
#pragma unroll
        for (int k = 0; k < 8; ++k) red[wave * 8 + k] = acc[k];
    }
    __syncthreads();
    if (t < 8) {
        float s = 0.f;
#pragma unroll
        for (int w = 0; w < 8; ++w) s += red[w * 8 + t];
        atomicAdd(&g_acc[t], s);
    }
}

__global__ void k_zero() {
    if (threadIdx.x < 8) g_acc[threadIdx.x] = 0.f;
}

__global__ void k_fin(float* __restrict__ out) {
    if (threadIdx.x == 0) {
        float s = 0.f;
#pragma unroll
        for (int k = 0; k < 4; ++k)
            s += g_acc[2 * k] * g_acc[2 * k] + g_acc[2 * k + 1] * g_acc[2 * k + 1];
        out[0] = (float)N0_ - s;
    }
}

extern "C" void kernel_launch(void* const* d_in, const int* in_sizes, int n_in,
                              void* d_out, int out_size, void* d_ws, size_t ws_size,
                              hipStream_t stream) {
    const float* c0r = (const float*)d_in[0];
    const float* c0i = (const float*)d_in[1];
    const float* c1r = (const float*)d_in[2];
    const float* c1i = (const float*)d_in[3];
    const float* ur  = (const float*)d_in[4];
    const float* ui  = (const float*)d_in[5];
    float* out = (float*)d_out;

    const size_t need = (size_t)N0_ * DIM_ * sizeof(float2);  // 128 MB intermediate
    k_zero<<<1, 64, 0, stream>>>();
    dim3 g1(1024, N0_);
    if (d_ws != nullptr && ws_size >= need) {
        float2* wsI = (float2*)d_ws;
        k_low<true><<<g1, 512, 0, stream>>>(c0r, c0i, ur, ui, wsI, nullptr, nullptr);
        k_high<true><<<1024, 512, 0, stream>>>(wsI, nullptr, nullptr, c1r, c1i, ur, ui);
    } else {
        // fallback: identity layout, in place into code0 planes (harness restores
        // d_in from pristine copies before every timed launch)
        float* oR = (float*)c0r;
        float* oJ = (float*)c0i;
        k_low<false><<<g1, 512, 0, stream>>>(c0r, c0i, ur, ui, nullptr, oR, oJ);
        k_high<false><<<1024, 512, 0, stream>>>(nullptr, oR, oJ, c1r, c1i, ur, ui);
    }
    k_fin<<<1, 64, 0, stream>>>(out);
}